// Round 12
// baseline (750.044 us; speedup 1.0000x reference)
//
#include <hip/hip_runtime.h>
#include <hip/hip_bf16.h>
#include <stdint.h>

typedef __hip_bfloat16 bf16;
typedef unsigned long long u64;
typedef unsigned short u16;

typedef __attribute__((ext_vector_type(8))) short bf16x8;
typedef __attribute__((ext_vector_type(4))) float f32x4;
typedef __attribute__((ext_vector_type(4))) int i32x4;

#define FIXCAP (1u << 20)
#define YQS 5312   // yq row stride (5306 padded to mult of 4 for aligned float4)

static __device__ __forceinline__ float ldin(const void* p, long i, int f32) {
    return f32 ? ((const float*)p)[i] : __bfloat162float(((const bf16*)p)[i]);
}

// expand 16 bits -> 16 i8 bytes of {0,1} (bit j = byte j). Cheaper than the +-1
// expansion (no ~ / *0xFE); the +-1 semantics are recovered via d = 2*S1 - T.
static __device__ __forceinline__ i32x4 expand16_01(unsigned m) {
    union { int4 s; i32x4 v; } u;
    u.s.x = (int)((((m         & 0xFu) * 0x00204081u) & 0x01010101u));
    u.s.y = (int)((((m >> 4)  & 0xFu) * 0x00204081u) & 0x01010101u);
    u.s.z = (int)((((m >> 8)  & 0xFu) * 0x00204081u) & 0x01010101u);
    u.s.w = (int)((((m >> 12) & 0xFu) * 0x00204081u) & 0x01010101u);
    return u.v;
}

// ---------------- probe: ctl[0]=0, ctl[1]=f32 flag ----------------
__global__ void k_probe(const void* x, unsigned* ctl) {
    int tid = threadIdx.x;
    int good = 0;
    for (int i = tid; i < 1024; i += 256) {
        float v = __bfloat162float(((const bf16*)x)[2 * i]);
        float a = fabsf(v);
        if (v == 0.0f || (isfinite(v) && a >= 1e-4f && a <= 100.0f)) good++;
    }
    __shared__ int s[256];
    s[tid] = good; __syncthreads();
    for (int st = 128; st > 0; st >>= 1) {
        if (tid < st) s[tid] += s[tid + st];
        __syncthreads();
    }
    if (tid == 0) { ctl[0] = 0u; ctl[1] = (s[0] >= 700) ? 0u : 1u; }
}

__global__ void k_sentinel(void* outv, const unsigned* ctl, float val) {
    int i = blockIdx.x * 256 + threadIdx.x;
    if (i >= 64000) return;
    if (ctl[1]) ((float*)outv)[i] = val;
    else ((bf16*)outv)[i] = __float2bfloat16(val);
}

// ---------------- mega prep ----------------
__device__ __forceinline__ void pack_convw_task(const void* w, uint2* wp, int Co, int f32,
                                                int bx, int tid) {
    int t = bx * 256 + tid;
    if (t >= Co * 41) return;
    int co = t / 41, k = t % 41;
    unsigned w0 = 0, w1 = 0;
    for (int c = 0; c < 32; c++)
        if (ldin(w, (co * 64 + c) * 41 + k, f32) > 0.f) w0 |= (1u << c);
    for (int c = 0; c < 32; c++)
        if (ldin(w, (co * 64 + 32 + c) * 41 + k, f32) > 0.f) w1 |= (1u << c);
    wp[t] = make_uint2(w0, w1);
}
__device__ __forceinline__ void pack_rows_task(const void* w, unsigned* wp, int rows, int F,
                                               int f32, int bx, int tid) {
    int Fw = F >> 5;
    int t = bx * 256 + tid;
    if (t >= rows * Fw) return;
    int r = t / Fw, wi = t % Fw;
    unsigned m = 0;
    for (int j = 0; j < 32; j++)
        if (ldin(w, (long)r * F + wi * 32 + j, f32) > 0.f) m |= (1u << j);
    wp[t] = m;
}

// conv1 A-fragment pack: K-layout kidx = 2*(c*44 + t) + h  (h: 0=hi,1=lo, same sign both)
// conv2 bit-packed weights (task 1): dword idx = (t*2 + p)*64 + lane; low16 = mask for
// m=2p, high16 = m=2p+1. Mask bit j = sign(w[co=16m+(lane&15)][ch=16*(lane>>4)+j][t]) > 0.
__global__ void k_prep(const void* x, const void* c1w, const void* c2w, const void* c3w,
                       const void* c4w, const void* c5w, const void* f1w, const void* f2w,
                       u16* afrag, unsigned* wb, uint2* w3p, uint2* w4p, uint2* w5p,
                       unsigned* fc1wp, unsigned* fc2wp, u64* stats, double* part0,
                       const unsigned* ctl) {
    int f32 = ctl[1];
    int task = blockIdx.y, bx = blockIdx.x, tid = threadIdx.x;
    switch (task) {
        case 0: {
            int t = bx * 256 + tid;
            if (t < 2304) {
                int m = t / 576, rem = t - m * 576;
                int ks = rem / 64, lane = rem - ks * 64;
                int li = lane & 15, hq = lane >> 4;
                int row = 16 * m + li;
                int g = 4 * ks + hq;
                int c = g / 11, t0 = 4 * (g - 11 * c);
                u16* outp = afrag + (size_t)t * 8;
                for (int i2 = 0; i2 < 4; i2++) {
                    int tt = t0 + i2;
                    u16 sv = 0;
                    if (g < 33 && tt <= 40) {
                        float wv = ldin(c1w, (row * 3 + c) * 41 + tt, f32);
                        sv = (wv > 0.f) ? (u16)0x3F80 : ((wv < 0.f) ? (u16)0xBF80 : (u16)0);
                    }
                    outp[2 * i2] = sv;       // hi slot
                    outp[2 * i2 + 1] = sv;   // lo slot (same sign)
                }
            }
        } break;
        case 1: {  // conv2 bit-packed weight masks
            int t = bx * 256 + tid;
            if (t < 5248) {
                int lane = t & 63, g = t >> 6;       // g = tt*2 + p, [0,82)
                int p = g & 1, tt = g >> 1;          // tt in [0,41)
                int li = lane & 15, hq = lane >> 4;
                unsigned d = 0;
#pragma unroll
                for (int mh = 0; mh < 2; mh++) {
                    int co = 16 * (2 * p + mh) + li;
                    unsigned msk = 0;
#pragma unroll
                    for (int j = 0; j < 16; j++) {
                        int c = 16 * hq + j;
                        if (ldin(c2w, (co * 64 + c) * 41 + tt, f32) > 0.f) msk |= 1u << j;
                    }
                    d |= msk << (16 * mh);
                }
                wb[t] = d;
            }
        } break;
        case 2: pack_convw_task(c3w, w3p, 64, f32, bx, tid); break;
        case 3: pack_convw_task(c4w, w4p, 64, f32, bx, tid); break;
        case 4: pack_convw_task(c5w, w5p, 32, f32, bx, tid); break;
        case 5: pack_rows_task(f1w, fc1wp, 1024, 832, f32, bx, tid); break;
        case 6: pack_rows_task(f2w, fc2wp, 1000, 1024, f32, bx, tid); break;
        case 7: {
            int i = bx * 256 + tid;
            if (i < 14400) stats[i] = 0ull;   // int-stats + yb(f64) + fixcnt
        } break;
        case 8: {
            if (bx >= 96) return;
            int c = bx >> 5, s = bx & 31;
            double s1 = 0, s2 = 0;
            for (int n = 0; n < 64; n++) {
                long base = (long)(n * 3 + c) * 16000;
                for (int l = s * 256 + tid; l < 16000; l += 32 * 256) {
                    double v = (double)ldin(x, base + l, f32);
                    s1 += v; s2 += v * v;
                }
            }
            __shared__ double a1[256], a2[256];
            a1[tid] = s1; a2[tid] = s2;
            __syncthreads();
            for (int st = 128; st > 0; st >>= 1) {
                if (tid < st) { a1[tid] += a1[tid + st]; a2[tid] += a2[tid + st]; }
                __syncthreads();
            }
            if (tid == 0) { part0[(c * 32 + s) * 2] = a1[0]; part0[(c * 32 + s) * 2 + 1] = a2[0]; }
        } break;
    }
}

// ---------------- conv1: bf16 MFMA with hi/lo split, SINGLE pass ----------------
__global__ __launch_bounds__(256, 3) void k_conv1(const void* __restrict__ x,
                                                  const double* __restrict__ part0,
                                                  const void* __restrict__ g0,
                                                  const void* __restrict__ b0,
                                                  const u16* __restrict__ afrag,
                                                  float* __restrict__ yq,
                                                  double* __restrict__ yb,
                                                  const unsigned* __restrict__ ctl) {
    __shared__ unsigned xs[8][140];        // parity streams, c=3 zero pad
    __shared__ float pool[4][48][20];      // [wave][pos][co] pad 16->20: 2-way banks
    __shared__ double sbuf[4][64][2];      // stats staging
    __shared__ float yst[16][68];          // per-m yq staging [c-within-m][lp-within-block]
    __shared__ float2 b0f[3];
    int f32 = ctl[1];
    int n = blockIdx.y, bx = blockIdx.x, tid = threadIdx.x;
    if (tid < 3) {   // fold bn0 finalize (f64 math, f32 apply)
        int c = tid;
        double s1 = 0, s2 = 0;
        for (int s = 0; s < 32; s++) { s1 += part0[(c * 32 + s) * 2]; s2 += part0[(c * 32 + s) * 2 + 1]; }
        double M = 64.0 * 16000.0;
        double mu = s1 / M, var = s2 / M - mu * mu;
        double A = (double)ldin(g0, c, f32) / sqrt(var + 1e-5);
        b0f[c] = make_float2((float)A, (float)((double)ldin(b0, c, f32) - mu * A));
    }
    __syncthreads();

    // fill parity streams (hi/lo bf16 interleaved per dword), f32 bn0 apply
    unsigned* xsf = &xs[0][0];
    for (int f = tid; f < 1120; f += 256) {
        int rc = f / 140, qi = f - rc * 140;
        int r = rc >> 2, c = rc & 3;
        unsigned dw = 0u;
        if (c < 3) {
            int xpos = 192 * bx + 2 * qi + r;
            if (xpos < 16000) {
                float2 pb = b0f[c];
                float v = fmaf(ldin(x, (long)(n * 3 + c) * 16000 + xpos, f32), pb.x, pb.y);
                v = fminf(fmaxf(v, -1.f), 1.f);
                bf16 h = __float2bfloat16(v);
                float hf = __bfloat162float(h);
                bf16 lo = __float2bfloat16(v - hf);
                dw = (unsigned)__bfloat16_as_ushort(h) | ((unsigned)__bfloat16_as_ushort(lo) << 16);
            }
        }
        xsf[f] = dw;
    }
    __syncthreads();

    int lane = tid & 63;
    int li = lane & 15, hq = lane >> 4;
    int w = __builtin_amdgcn_readfirstlane(tid >> 6);

    f32x4 zz = {0.f, 0.f, 0.f, 0.f};
    f32x4 acc[4][3];
#pragma unroll
    for (int m = 0; m < 4; m++)
#pragma unroll
        for (int nf = 0; nf < 3; nf++) acc[m][nf] = zz;

    int boff[3];
#pragma unroll
    for (int nf = 0; nf < 3; nf++) {
        int pl = 48 * w + 16 * nf + li;
        boff[nf] = (pl & 1) * 560 + (pl >> 1);
    }

    const bf16x8* ag = (const bf16x8*)afrag;
#pragma unroll 1
    for (int ks = 0; ks < 9; ks++) {
        int g = 4 * ks + hq;
        int c = g / 11;
        int kb = c * 140 + 4 * (g - 11 * c);
        bf16x8 a0 = ag[(0 * 9 + ks) * 64 + lane];
        bf16x8 a1 = ag[(1 * 9 + ks) * 64 + lane];
        bf16x8 a2 = ag[(2 * 9 + ks) * 64 + lane];
        bf16x8 a3 = ag[(3 * 9 + ks) * 64 + lane];
#pragma unroll
        for (int nf = 0; nf < 3; nf++) {
            const unsigned* bp = xsf + boff[nf] + kb;
            union { int4 i4; bf16x8 v; } u;
            u.i4 = make_int4(bp[0], bp[1], bp[2], bp[3]);
            acc[0][nf] = __builtin_amdgcn_mfma_f32_16x16x32_bf16(a0, u.v, acc[0][nf], 0, 0, 0);
            acc[1][nf] = __builtin_amdgcn_mfma_f32_16x16x32_bf16(a1, u.v, acc[1][nf], 0, 0, 0);
            acc[2][nf] = __builtin_amdgcn_mfma_f32_16x16x32_bf16(a2, u.v, acc[2][nf], 0, 0, 0);
            acc[3][nf] = __builtin_amdgcn_mfma_f32_16x16x32_bf16(a3, u.v, acc[3][nf], 0, 0, 0);
        }
    }

    int lp0 = 64 * bx + 16 * w;
#pragma unroll
    for (int m = 0; m < 4; m++) {        // FULL unroll: acc index must be static
#pragma unroll
        for (int nf = 0; nf < 3; nf++)
            *(f32x4*)&pool[w][16 * nf + li][4 * hq] = acc[m][nf];
        double s = 0.0, q = 0.0;
        float mqv[4];
#pragma unroll
        for (int i = 0; i < 4; i++) {
            int pc = hq + 4 * i;
            float mq = fmaxf(fmaxf(pool[w][3 * pc][li], pool[w][3 * pc + 1][li]),
                             pool[w][3 * pc + 2][li]);
            mqv[i] = mq;
            if (lp0 + pc < 5306) {
                double d = (double)mq;
                s += d; q += d * d;
            }
        }
        s += __shfl_down(s, 32, 64); s += __shfl_down(s, 16, 64);
        q += __shfl_down(q, 32, 64); q += __shfl_down(q, 16, 64);
        if (lane < 16) { sbuf[w][16 * m + lane][0] = s; sbuf[w][16 * m + lane][1] = q; }
        // stage mq for this m -> yst, then coalesced row write (values beyond
        // lp 5305 land in the YQS pad, never read by pack_y)
#pragma unroll
        for (int i = 0; i < 4; i++)
            yst[li][16 * w + hq + 4 * i] = mqv[i];
        __syncthreads();
        {
            int r = tid >> 4, c4 = (tid & 15) * 4;
            float4 v = *(const float4*)&yst[r][c4];
            *(float4*)&yq[((size_t)n * 64 + 16 * m + r) * YQS + 64 * bx + c4] = v;
        }
        __syncthreads();
    }
    if (tid < 64) {
        double s = sbuf[0][tid][0] + sbuf[1][tid][0] + sbuf[2][tid][0] + sbuf[3][tid][0];
        double q = sbuf[0][tid][1] + sbuf[1][tid][1] + sbuf[2][tid][1] + sbuf[3][tid][1];
        int sbk = bx & 15;
        atomicAdd(&yb[(tid * 16 + sbk) * 2], s);
        atomicAdd(&yb[(tid * 16 + sbk) * 2 + 1], q);
    }
}

// ---------------- pack_y: streaming sign + borderline list ----------------
__global__ void k_pack_y(const float* __restrict__ yq, const double* __restrict__ yb,
                         const void* g1, const void* b1,
                         uint2* __restrict__ xp,
                         unsigned* __restrict__ fixcnt, unsigned* __restrict__ fixlist,
                         const unsigned* __restrict__ ctl) {
    __shared__ double2 pqs[64];   // (A, B) per channel
    int f32 = ctl[1];
    int tid = threadIdx.x;
    if (tid < 64) {
        int c = tid;
        double s1 = 0, s2 = 0;
        for (int s = 0; s < 16; s++) { s1 += yb[(c * 16 + s) * 2]; s2 += yb[(c * 16 + s) * 2 + 1]; }
        double M = 64.0 * 5306.0;
        double mu = s1 / M;
        double var = s2 / M - mu * mu;
        double A = (double)ldin(g1, c, f32) / sqrt(var + 1e-5);
        pqs[c] = make_double2(A, (double)ldin(b1, c, f32) - mu * A);
    }
    __syncthreads();
    int n = blockIdx.y;
    int l = blockIdx.x * 256 + tid;
    if (l >= 5306) return;
    unsigned w0 = 0, w1 = 0;
    for (int c = 0; c < 64; c++) {
        double2 p = pqs[c];
        double v = (double)yq[((size_t)n * 64 + c) * YQS + l] * p.x + p.y;
        if (fabs(v) < 2e-3 * fabs(p.x)) {
            unsigned idx = atomicAdd(fixcnt, 1u);
            if (idx < FIXCAP) fixlist[idx] = ((unsigned)n << 19) | ((unsigned)c << 13) | (unsigned)l;
        }
        if (v > 0.0) { if (c < 32) w0 |= 1u << c; else w1 |= 1u << (c - 32); }
    }
    xp[(size_t)n * 5306 + l] = make_uint2(w0, w1);
}

// ---------------- k_fix: exact f64 recompute of listed borderline outputs ----------------
__global__ void k_fix(const unsigned* __restrict__ fixcnt, const unsigned* __restrict__ fixlist,
                      const double* __restrict__ yb, const void* g1, const void* b1,
                      const void* __restrict__ x, const void* __restrict__ c1w,
                      const double* __restrict__ part0, const void* g0, const void* b0,
                      unsigned* __restrict__ x2p, const unsigned* __restrict__ ctl) {
    int f32 = ctl[1];
    unsigned cnt = min(*fixcnt, FIXCAP);
    for (unsigned t = blockIdx.x * 256 + threadIdx.x; t < cnt; t += gridDim.x * 256) {
        unsigned e = fixlist[t];
        int n = e >> 19, c = (e >> 13) & 63, l = e & 8191;
        double s1 = 0, s2 = 0;
        for (int s = 0; s < 16; s++) { s1 += yb[(c * 16 + s) * 2]; s2 += yb[(c * 16 + s) * 2 + 1]; }
        double M = 64.0 * 5306.0;
        double mu = s1 / M, var = s2 / M - mu * mu;
        double A = (double)ldin(g1, c, f32) / sqrt(var + 1e-5);
        double B = (double)ldin(b1, c, f32) - mu * A;
        double best = -1e300;
        for (int r = 0; r < 3; r++) {
            int pp = 3 * l + r;
            double acc = 0.0;
            for (int cc = 0; cc < 3; cc++) {
                double p1 = 0, p2 = 0;
                for (int s = 0; s < 32; s++) { p1 += part0[(cc * 32 + s) * 2]; p2 += part0[(cc * 32 + s) * 2 + 1]; }
                double M0 = 64.0 * 16000.0;
                double mu0 = p1 / M0, var0 = p2 / M0 - mu0 * mu0;
                double A0 = (double)ldin(g0, cc, f32) / sqrt(var0 + 1e-5);
                double B0 = (double)ldin(b0, cc, f32) - mu0 * A0;
                for (int k = 0; k < 41; k++) {
                    float wf = ldin(c1w, (c * 3 + cc) * 41 + k, f32);
                    double sgn = (wf > 0.f) ? 1.0 : ((wf < 0.f) ? -1.0 : 0.0);
                    double xv = (double)ldin(x, (long)(n * 3 + cc) * 16000 + pp + 2 * k, f32);
                    xv = fmin(fmax(xv * A0 + B0, -1.0), 1.0);
                    acc = fma(sgn, xv, acc);
                }
            }
            best = fmax(best, acc);
        }
        double v = best * A + B;
        unsigned* word = &x2p[((size_t)n * 5306 + l) * 2 + (c >> 5)];
        unsigned bit = 1u << (c & 31);
        if (v > 0.0) atomicOr(word, bit);
        else atomicAnd(word, ~bit);
    }
}

// ---------------- conv2: i8 MFMA with {0,1} weights + column-sum correction ----------------
// grid (28, 32) x2 dispatches (nbase 0/32 — halves each dispatch so the profiler's
// top-5 can surface the hidden #2.. kernels). Identity: x in {+-1}, w in {+-1}:
// d = sum(+-w)(+-x) = 2*S1 - T, S1 = MFMA with A' = (w>0) in {0,1} (expansion is
// ~35% cheaper: no ~/*0xFE), T[pl] = sum_t sum_c x = 41-window sum of per-entry
// column sums cs = 2*popc(mask)-64 (co-independent, computed once). Exact ints;
// mv = (2624-d)>>1 bit-identical. VALUBusy was the only busy pipe (37%, r11).
__global__ __launch_bounds__(256, 3) void k_conv_i8(const uint2* __restrict__ xp,
                                                    const unsigned* __restrict__ wb,
                                                    u16* __restrict__ mout,
                                                    u64* __restrict__ stat, int nbase) {
    __shared__ __align__(16) char arena[44608];
    unsigned* xsd = (unsigned*)arena;                       // [0,21760): 2*136 x 80 B
    unsigned* wlds = (unsigned*)(arena + 21760);            // [21760,42752): 5248 dwords
    int* Tarr = (int*)(arena + 42752);                      // [42752,43520): 192 ints
    int* csA  = (int*)(arena + 43520);                      // [43520,44608): 272 ints
    int n = nbase + blockIdx.y, bx = blockIdx.x, tid = threadIdx.x;
    int base = 192 * bx;

    // stage bit-packed weights (once per block, coalesced)
    for (int i = tid; i < 5248; i += 256) wlds[i] = wb[i];

    // unpack input bit-masks -> +-1 i8 (byte = bit ? 0x01 : 0xFF) + column sums
    for (int e = tid; e < 272; e += 256) {
        int pos = base + e;
        int r = e & 1, qi = e >> 1;
        unsigned* dst = xsd + (r * 136 + qi) * 20;
        unsigned d[16];
        int cs = 0;
        if (pos < 5306) {
            uint2 mk = xp[(size_t)n * 5306 + pos];
            cs = 2 * (__popc(mk.x) + __popc(mk.y)) - 64;
#pragma unroll
            for (int dw = 0; dw < 8; dw++) {
                unsigned nib = (mk.x >> (4 * dw)) & 0xFu;
                unsigned sp = (nib * 0x00204081u) & 0x01010101u;
                d[dw] = ~(sp * 0xFEu);
            }
#pragma unroll
            for (int dw = 0; dw < 8; dw++) {
                unsigned nib = (mk.y >> (4 * dw)) & 0xFu;
                unsigned sp = (nib * 0x00204081u) & 0x01010101u;
                d[8 + dw] = ~(sp * 0xFEu);
            }
        } else {
#pragma unroll
            for (int dw = 0; dw < 16; dw++) d[dw] = 0u;
        }
#pragma unroll
        for (int v4 = 0; v4 < 4; v4++)
            *(uint4*)(dst + 4 * v4) = make_uint4(d[4 * v4], d[4 * v4 + 1],
                                                 d[4 * v4 + 2], d[4 * v4 + 3]);
        csA[r * 136 + qi] = cs;
    }
    __syncthreads();

    // T[pl] = 41-window sum of column sums for pl's parity stream (one-time)
    if (tid < 192) {
        int r = tid & 1, q = tid >> 1;
        int s = 0;
        for (int k = 0; k < 41; k++) s += csA[r * 136 + q + k];
        Tarr[tid] = s;
    }   // Tarr readers are after the post-K-loop barrier

    int lane = tid & 63;
    int li = lane & 15, hq = lane >> 4;
    int w = __builtin_amdgcn_readfirstlane(tid >> 6);

    i32x4 zz = {0, 0, 0, 0};
    i32x4 acc[4][3];
#pragma unroll
    for (int m = 0; m < 4; m++)
#pragma unroll
        for (int nf = 0; nf < 3; nf++) acc[m][nf] = zz;

    int boff[3];
#pragma unroll
    for (int nf = 0; nf < 3; nf++) {
        int pl = 48 * w + 16 * nf + li;
        boff[nf] = ((pl & 1) * 136 + (pl >> 1)) * 80 + 16 * hq;
    }

    const char* xsb = (const char*)xsd;
    const unsigned* wl = wlds + lane;

    // K-loop: pure LDS + VALU + MFMA; A' in {0,1} (cheap expansion)
#pragma unroll 1
    for (int t = 0; t < 41; t++) {
        unsigned w01 = wl[(t * 2 + 0) * 64];
        unsigned w23 = wl[(t * 2 + 1) * 64];
        i32x4 a0 = expand16_01(w01 & 0xFFFFu);
        i32x4 a1 = expand16_01(w01 >> 16);
        i32x4 a2 = expand16_01(w23 & 0xFFFFu);
        i32x4 a3 = expand16_01(w23 >> 16);
#pragma unroll
        for (int nf = 0; nf < 3; nf++) {
            i32x4 b = *(const i32x4*)(xsb + boff[nf] + t * 80);
            acc[0][nf] = __builtin_amdgcn_mfma_i32_16x16x64_i8(a0, b, acc[0][nf], 0, 0, 0);
            acc[1][nf] = __builtin_amdgcn_mfma_i32_16x16x64_i8(a1, b, acc[1][nf], 0, 0, 0);
            acc[2][nf] = __builtin_amdgcn_mfma_i32_16x16x64_i8(a2, b, acc[2][nf], 0, 0, 0);
            acc[3][nf] = __builtin_amdgcn_mfma_i32_16x16x64_i8(a3, b, acc[3][nf], 0, 0, 0);
        }
    }

    // epilogue (aliases arena[0,24576); Tarr/csA regions untouched):
    // d_r = 2*S1 - Tarr[pl]; pool-of-3 + stats; mt stage; coalesced write
    __syncthreads();   // all waves done reading xsd/wlds; Tarr writes visible
    int (*pooli)[48][20] = (int (*)[48][20])arena;          // 15360 B
    u16 (*mt)[72] = (u16 (*)[72])(arena + 15360);           // 9216 B
    int sbk = bx & 15;
#pragma unroll
    for (int m = 0; m < 4; m++) {        // FULL unroll: acc index must be static
#pragma unroll
        for (int nf = 0; nf < 3; nf++)
            *(i32x4*)&pooli[w][16 * nf + li][4 * hq] = acc[m][nf];
        int c = 16 * m + li;
        unsigned s = 0, q = 0;
#pragma unroll
        for (int i = 0; i < 4; i++) {
            int pc = hq + 4 * i;
            int d0 = 2 * pooli[w][3 * pc][li]     - Tarr[48 * w + 3 * pc];
            int d1 = 2 * pooli[w][3 * pc + 1][li] - Tarr[48 * w + 3 * pc + 1];
            int d2 = 2 * pooli[w][3 * pc + 2][li] - Tarr[48 * w + 3 * pc + 2];
            int d = max(max(d0, d1), d2);
            int mv = (2624 - d) >> 1;
            mt[c][16 * w + pc] = (u16)mv;
            int lp = 64 * bx + 16 * w + pc;
            if (lp < 1742) {
                s += (unsigned)mv;
                q += (unsigned)(mv * mv);
            }
        }
        s += __shfl_down(s, 32, 64); s += __shfl_down(s, 16, 64);
        q += __shfl_down(q, 32, 64); q += __shfl_down(q, 16, 64);
        if (lane < 16) {
            atomicAdd(&stat[((16 * m + lane) * 16 + sbk) * 2], (u64)s);
            atomicAdd(&stat[((16 * m + lane) * 16 + sbk) * 2 + 1], (u64)q);
        }
    }
    __syncthreads();
    {
        int c = tid >> 2, seg = tid & 3;
        int lp0 = 64 * bx + seg * 16;
        size_t rowb = ((size_t)n * 64 + c) * 1742;
        const u16* mp = &mt[c][seg * 16];
        if (lp0 + 15 < 1742) {
            unsigned* op = (unsigned*)(mout + rowb + lp0);
#pragma unroll
            for (int j = 0; j < 8; j++)
                op[j] = (unsigned)mp[2 * j] | ((unsigned)mp[2 * j + 1] << 16);
        } else {
            for (int j = 0; j < 16; j++) {
                int lp = lp0 + j;
                if (lp < 1742) mout[rowb + lp] = mp[j];
            }
        }
    }
}

// ---------------- binary conv with fused BN(m)+pack staging (conv3/4) ----------------
__global__ __launch_bounds__(256) void k_conv_binm(const u16* __restrict__ min_,
                                                   const u64* __restrict__ statIn,
                                                   const void* g, const void* b, double M,
                                                   const uint2* __restrict__ wp,
                                                   u16* __restrict__ mout,
                                                   u64* __restrict__ statOut,
                                                   int Lp, int Lin, int Co,
                                                   const unsigned* __restrict__ ctl) {
    __shared__ double2 pqs[64];
    __shared__ uint2 xt[272];
    int f32 = ctl[1];
    int n = blockIdx.y, tid = threadIdx.x;
    if (tid < 64) {
        int c = tid;
        u64 s1 = 0, s2 = 0;
        for (int s = 0; s < 16; s++) { s1 += statIn[(c * 16 + s) * 2]; s2 += statIn[(c * 16 + s) * 2 + 1]; }
        double mu = (double)s1 / M;
        double varm = (double)s2 / M - mu * mu;
        double A = (double)ldin(g, c, f32) / sqrt(4.0 * varm + 1e-5);
        pqs[c] = make_double2(-2.0 * A, 2.0 * A * mu + (double)ldin(b, c, f32));
    }
    __syncthreads();
    int base = blockIdx.x * 192;
    for (int i = tid; i < 272; i += 256) {
        int pos = base + i;
        unsigned w0 = 0, w1 = 0;
        if (pos < Lin) {
            const u16* mp = min_ + (size_t)n * 64 * Lin + pos;
#pragma unroll 4
            for (int c = 0; c < 32; c++) {
                double2 p = pqs[c];
                if ((double)mp[(size_t)c * Lin] * p.x + p.y > 0.0) w0 |= 1u << c;
            }
#pragma unroll 4
            for (int c = 0; c < 32; c++) {
                double2 p = pqs[c + 32];
                if ((double)mp[(size_t)(c + 32) * Lin] * p.x + p.y > 0.0) w1 |= 1u << c;
            }
        }
        xt[i] = make_uint2(w0, w1);
    }
    __syncthreads();

    int lane = tid & 63;
    int wave = __builtin_amdgcn_readfirstlane(tid >> 6);
    int co0 = blockIdx.z * 32 + wave * 8;
    int lp = blockIdx.x * 64 + lane;

    int acc[8][3] = {};
    uint2 xa = xt[3 * lane];
    for (int k = 0; k < 41; k++) {
        uint2 xb = xt[3 * lane + 2 * k + 1];
        uint2 xc = xt[3 * lane + 2 * k + 2];
#pragma unroll
        for (int j = 0; j < 8; j++) {
            uint2 w = wp[(co0 + j) * 41 + k];
            acc[j][0] += __popc(w.x ^ xa.x) + __popc(w.y ^ xa.y);
            acc[j][1] += __popc(w.x ^ xb.x) + __popc(w.y ^ xb.y);
            acc[j][2] += __popc(w.x ^ xc.x) + __popc(w.y ^ xc.y);
        }
        xa = xc;
    }
    bool ok = lp < Lp;
    int sb = blockIdx.x & 15;
#pragma unroll
    for (int j = 0; j < 8; j++) {
        int m = min(min(acc[j][0], acc[j][1]), acc[j][2]);
        if (ok) mout[((size_t)n * 64 + co0 + j) * Lp + lp] = (u16)m;
        if (statOut) {
            unsigned s = ok ? (unsigned)m : 0u;
            unsigned q = ok ? (unsigned)(m * m) : 0u;
            for (int off = 32; off > 0; off >>= 1) {
                s += __shfl_down(s, off, 64);
                q += __shfl_down(q, off, 64);
            }
            if (lane == 0) {
                atomicAdd(&statOut[((co0 + j) * 16 + sb) * 2], (u64)s);
                atomicAdd(&statOut[((co0 + j) * 16 + sb) * 2 + 1], (u64)q);
            }
        }
    }
}

// ---------------- conv5 + fc1 fused ----------------
__global__ void k_c5fc1(const u16* __restrict__ m4, const u64* __restrict__ s4,
                        const void* g4, const void* b4,
                        const uint2* __restrict__ w5p, const void* __restrict__ b5,
                        const unsigned* __restrict__ fc1wp, u16* __restrict__ acc1,
                        u64* __restrict__ s5, const unsigned* __restrict__ ctl) {
    __shared__ double2 pqs[64];
    __shared__ uint2 xt[280];
    __shared__ int m5s[32][26];
    __shared__ unsigned xw[26];
    int f32 = ctl[1];
    int n = blockIdx.x, tid = threadIdx.x;
    const int Lin = 158;
    if (tid < 64) {
        int c = tid;
        u64 s1 = 0, s2 = 0;
        for (int s = 0; s < 16; s++) { s1 += s4[(c * 16 + s) * 2]; s2 += s4[(c * 16 + s) * 2 + 1]; }
        double M = 64.0 * 158.0;
        double mu = (double)s1 / M;
        double varm = (double)s2 / M - mu * mu;
        double A = (double)ldin(g4, c, f32) / sqrt(4.0 * varm + 1e-5);
        pqs[c] = make_double2(-2.0 * A, 2.0 * A * mu + (double)ldin(b4, c, f32));
    }
    __syncthreads();
    for (int i = tid; i < 280; i += 256) {
        unsigned w0 = 0, w1 = 0;
        if (i < Lin) {
            const u16* mp = m4 + (size_t)n * 64 * Lin + i;
#pragma unroll 4
            for (int c = 0; c < 32; c++) {
                double2 p = pqs[c];
                if ((double)mp[(size_t)c * Lin] * p.x + p.y > 0.0) w0 |= 1u << c;
            }
#pragma unroll 4
            for (int c = 0; c < 32; c++) {
                double2 p = pqs[c + 32];
                if ((double)mp[(size_t)(c + 32) * Lin] * p.x + p.y > 0.0) w1 |= 1u << c;
            }
        }
        xt[i] = make_uint2(w0, w1);
    }
    __syncthreads();

    int lane = tid & 63;
    int wave = __builtin_amdgcn_readfirstlane(tid >> 6);
    int co0 = wave * 8;
    int acc[8][3] = {};
    uint2 xa = xt[3 * lane];
    for (int k = 0; k < 41; k++) {
        uint2 xb = xt[3 * lane + 2 * k + 1];
        uint2 xc = xt[3 * lane + 2 * k + 2];
#pragma unroll
        for (int j = 0; j < 8; j++) {
            uint2 w = w5p[(co0 + j) * 41 + k];
            acc[j][0] += __popc(w.x ^ xa.x) + __popc(w.y ^ xa.y);
            acc[j][1] += __popc(w.x ^ xb.x) + __popc(w.y ^ xb.y);
            acc[j][2] += __popc(w.x ^ xc.x) + __popc(w.y ^ xc.y);
        }
        xa = xc;
    }
    if (lane < 26) {
#pragma unroll
        for (int j = 0; j < 8; j++)
            m5s[co0 + j][lane] = min(min(acc[j][0], acc[j][1]), acc[j][2]);
    }
    __syncthreads();
    if (tid < 26) {
        unsigned mask = 0;
        for (int j = 0; j < 32; j++) {
            int f = tid * 32 + j, c = f / 26, l = f % 26;
            double yv = 2624.0 - 2.0 * (double)m5s[c][l] + (double)ldin(b5, c, f32);
            if (yv > 0.0) mask |= 1u << j;
        }
        xw[tid] = mask;
    }
    __syncthreads();
#pragma unroll
    for (int i = 0; i < 4; i++) {
        int j = tid + i * 256;
        unsigned a = 0;
        for (int w = 0; w < 26; w++) a += __popc(xw[w] ^ fc1wp[j * 26 + w]);
        acc1[n * 1024 + j] = (u16)a;
        atomicAdd(&s5[j * 2], (u64)a);
        atomicAdd(&s5[j * 2 + 1], (u64)(a * a));
    }
}

// ---------------- fc2 (+bn5 fold) and lsm (+bn6 fold) ----------------
__global__ void k_fc2(const u16* __restrict__ acc1, const u64* __restrict__ s5,
                      const void* g5, const void* b5, const unsigned* __restrict__ fc2wp,
                      u16* __restrict__ acc2, u64* __restrict__ s6, const unsigned* ctl) {
    __shared__ double2 pq5s[1024];
    __shared__ unsigned xw[32];
    int f32 = ctl[1];
    int n = blockIdx.y, tid = threadIdx.x;
    for (int f = tid; f < 1024; f += 256) {
        u64 a1 = s5[f * 2], a2 = s5[f * 2 + 1];
        double mu = (double)a1 / 64.0;
        double varm = (double)a2 / 64.0 - mu * mu;
        double A = (double)ldin(g5, f, f32) / sqrt(4.0 * varm + 1e-5);
        pq5s[f] = make_double2(-2.0 * A, 2.0 * A * mu + (double)ldin(b5, f, f32));
    }
    __syncthreads();
    if (tid < 32) {
        unsigned mask = 0;
        for (int j = 0; j < 32; j++) {
            int f = tid * 32 + j;
            double2 p = pq5s[f];
            if ((double)acc1[n * 1024 + f] * p.x + p.y > 0.0) mask |= 1u << j;
        }
        xw[tid] = mask;
    }
    __syncthreads();
    int j = blockIdx.x * 256 + tid;
    if (j >= 1000) return;
    unsigned a = 0;
    for (int w = 0; w < 32; w++) a += __popc(xw[w] ^ fc2wp[j * 32 + w]);
    acc2[n * 1000 + j] = (u16)a;
    atomicAdd(&s6[j * 2], (u64)a);
    atomicAdd(&s6[j * 2 + 1], (u64)(a * a));
}

__global__ void k_lsm(const u16* __restrict__ acc2, const u64* __restrict__ s6,
                      const void* g6, const void* b6, const unsigned* ctl, void* outv) {
    int n = blockIdx.x, tid = threadIdx.x;
    int f32 = ctl[1];
    __shared__ double red[256];
    double v[4];
    double mx = -1e300;
#pragma unroll
    for (int i = 0; i < 4; i++) {
        int j = tid + i * 256;
        if (j < 1000) {
            u64 a1 = s6[j * 2], a2 = s6[j * 2 + 1];
            double mu = (double)a1 / 64.0;
            double varm = (double)a2 / 64.0 - mu * mu;
            double A = (double)ldin(g6, j, f32) / sqrt(4.0 * varm + 1e-5);
            v[i] = (double)acc2[n * 1000 + j] * (-2.0 * A) + (2.0 * A * mu + (double)ldin(b6, j, f32));
            mx = fmax(mx, v[i]);
        } else v[i] = -1e300;
    }
    red[tid] = mx; __syncthreads();
    for (int s = 128; s > 0; s >>= 1) {
        if (tid < s) red[tid] = fmax(red[tid], red[tid + s]);
        __syncthreads();
    }
    mx = red[0]; __syncthreads();
    double sum = 0.0;
#pragma unroll
    for (int i = 0; i < 4; i++) {
        int j = tid + i * 256;
        if (j < 1000) sum += exp(v[i] - mx);
    }
    red[tid] = sum; __syncthreads();
    for (int s = 128; s > 0; s >>= 1) {
        if (tid < s) red[tid] += red[tid + s];
        __syncthreads();
    }
    double ls = log(red[0]);
#pragma unroll
    for (int i = 0; i < 4; i++) {
        int j = tid + i * 256;
        if (j < 1000) {
            float r = (float)(v[i] - mx - ls);
            if (!isfinite(r)) r = -700.0f;
            if (f32) ((float*)outv)[n * 1000 + j] = r;
            else ((bf16*)outv)[n * 1000 + j] = __float2bfloat16(r);
        }
    }
}

extern "C" void kernel_launch(void* const* d_in, const int* in_sizes, int n_in,
                              void* d_out, int out_size, void* d_ws, size_t ws_size,
                              hipStream_t stream) {
    const void* x       = d_in[0];
    const void* bn0_g   = d_in[1];
    const void* bn0_b   = d_in[2];
    const void* conv1_w = d_in[3];
    const void* bn1_g   = d_in[5];
    const void* bn1_b   = d_in[6];
    const void* conv2_w = d_in[7];
    const void* bn2_g   = d_in[9];
    const void* bn2_b   = d_in[10];
    const void* conv3_w = d_in[11];
    const void* bn3_g   = d_in[13];
    const void* bn3_b   = d_in[14];
    const void* conv4_w = d_in[15];
    const void* bn4_g   = d_in[17];
    const void* bn4_b   = d_in[18];
    const void* conv5_w = d_in[19];
    const void* conv5_b = d_in[20];
    const void* fc1_w   = d_in[21];
    const void* bn5_g   = d_in[23];
    const void* bn5_b   = d_in[24];
    const void* fc2_w   = d_in[25];
    const void* bn6_g   = d_in[27];
    const void* bn6_b   = d_in[28];

    char* wsb = (char*)d_ws;
    size_t off = 0;
    auto alloc = [&](size_t bytes) -> void* {
        off = (off + 255) & ~(size_t)255;
        void* p = wsb + off;
        off += bytes;
        return p;
    };

    unsigned* ctl   = (unsigned*)alloc(256);
    unsigned* x2p   = (unsigned*)alloc(2716672);       // 5306*64 uint2
    float*    yq    = (float*)alloc((size_t)64 * 64 * YQS * 4);  // 87 MB pooled conv1
    u16*      m2    = (u16*)alloc(14270464);
    u16*      m3    = (u16*)alloc(4538368);
    u16*      m4    = (u16*)alloc(1294336);
    u16*      acc1  = (u16*)alloc(131072);
    u16*      acc2  = (u16*)alloc(128000);
    u16*      afrag = (u16*)alloc(36864);              // conv1 bf16 A-fragments
    unsigned* wb    = (unsigned*)alloc(20992);         // conv2 bit-packed weights (lane layout)
    uint2*    w3p   = (uint2*)alloc(20992);
    uint2*    w4p   = (uint2*)alloc(20992);
    uint2*    w5p   = (uint2*)alloc(10496);
    unsigned* fc1wp = (unsigned*)alloc(106496);
    unsigned* fc2wp = (unsigned*)alloc(128000);
    u64*      stats = (u64*)alloc(14400 * 8);          // s2|s3|s4|s5|s6|..|yb(f64)|fixcnt
    double*   part0 = (double*)alloc(2048);
    unsigned* fixlist = (unsigned*)alloc(FIXCAP * 4);  // 4 MB
    size_t need = (off + 255) & ~(size_t)255;

    u64* s2 = stats;
    u64* s3 = stats + 2048;
    u64* s4 = stats + 4096;
    u64* s5 = stats + 6144;
    u64* s6 = stats + 8192;
    double* yb = (double*)(stats + 12288);             // 2048 f64 bn1 buckets
    unsigned* fixcnt = (unsigned*)(stats + 14340);

    k_probe<<<1, 256, 0, stream>>>(x, ctl);

    if (n_in != 29) {
        k_sentinel<<<250, 256, 0, stream>>>(d_out, ctl, -(3000.0f + (float)n_in));
        return;
    }
    if (ws_size < need) {
        k_sentinel<<<250, 256, 0, stream>>>(d_out, ctl, -1500.0f);
        return;
    }

    k_prep<<<dim3(125, 9), 256, 0, stream>>>(x, conv1_w, conv2_w, conv3_w, conv4_w, conv5_w,
                                             fc1_w, fc2_w, afrag, wb, w3p, w4p, w5p,
                                             fc1wp, fc2wp, stats, part0, ctl);

    // single conv pass: pooled mq -> yq (coalesced) + stats -> yb
    k_conv1<<<dim3(83, 64), 256, 0, stream>>>(x, part0, bn0_g, bn0_b, afrag, yq, yb, ctl);
    k_pack_y<<<dim3(21, 64), 256, 0, stream>>>(yq, yb, bn1_g, bn1_b, (uint2*)x2p,
                                               fixcnt, fixlist, ctl);
    k_fix<<<64, 256, 0, stream>>>(fixcnt, fixlist, yb, bn1_g, bn1_b, x, conv1_w,
                                  part0, bn0_g, bn0_b, x2p, ctl);

    // conv2 split into two half-batch dispatches (profiler visibility of #2.. kernels)
    k_conv_i8<<<dim3(28, 32), 256, 0, stream>>>((const uint2*)x2p, wb, m2, s2, 0);
    k_conv_i8<<<dim3(28, 32), 256, 0, stream>>>((const uint2*)x2p, wb, m2, s2, 32);
    k_conv_binm<<<dim3(9, 64, 2), 256, 0, stream>>>(m2, s2, bn2_g, bn2_b, 64.0 * 1742.0,
                                                    w3p, m3, s3, 554, 1742, 64, ctl);
    k_conv_binm<<<dim3(3, 64, 2), 256, 0, stream>>>(m3, s3, bn3_g, bn3_b, 64.0 * 554.0,
                                                    w4p, m4, s4, 158, 554, 64, ctl);

    k_c5fc1<<<64, 256, 0, stream>>>(m4, s4, bn4_g, bn4_b, w5p, conv5_b, fc1wp, acc1, s5, ctl);
    k_fc2<<<dim3(4, 64), 256, 0, stream>>>(acc1, s5, bn5_g, bn5_b, fc2wp, acc2, s6, ctl);
    k_lsm<<<64, 256, 0, stream>>>(acc2, s6, bn6_g, bn6_b, ctl, d_out);
}

// Round 13
// 651.973 us; speedup vs baseline: 1.1504x; 1.1504x over previous
//
#include <hip/hip_runtime.h>
#include <hip/hip_bf16.h>
#include <stdint.h>

typedef __hip_bfloat16 bf16;
typedef unsigned long long u64;
typedef unsigned short u16;

typedef __attribute__((ext_vector_type(8))) short bf16x8;
typedef __attribute__((ext_vector_type(4))) float f32x4;
typedef __attribute__((ext_vector_type(4))) int i32x4;

#define FIXCAP (1u << 20)
#define YQS 5312   // yq row stride (5306 padded to mult of 4 for aligned float4)

static __device__ __forceinline__ float ldin(const void* p, long i, int f32) {
    return f32 ? ((const float*)p)[i] : __bfloat162float(((const bf16*)p)[i]);
}

// expand 16 bits -> 16 i8 bytes of {0,1} (bit j = byte j). Cheaper than the +-1
// expansion (no ~ / *0xFE); the +-1 semantics are recovered via d = 2*S1 - T.
static __device__ __forceinline__ i32x4 expand16_01(unsigned m) {
    union { int4 s; i32x4 v; } u;
    u.s.x = (int)((((m         & 0xFu) * 0x00204081u) & 0x01010101u));
    u.s.y = (int)((((m >> 4)  & 0xFu) * 0x00204081u) & 0x01010101u);
    u.s.z = (int)((((m >> 8)  & 0xFu) * 0x00204081u) & 0x01010101u);
    u.s.w = (int)((((m >> 12) & 0xFu) * 0x00204081u) & 0x01010101u);
    return u.v;
}

// ---------------- probe: ctl[0]=0, ctl[1]=f32 flag ----------------
__global__ void k_probe(const void* x, unsigned* ctl) {
    int tid = threadIdx.x;
    int good = 0;
    for (int i = tid; i < 1024; i += 256) {
        float v = __bfloat162float(((const bf16*)x)[2 * i]);
        float a = fabsf(v);
        if (v == 0.0f || (isfinite(v) && a >= 1e-4f && a <= 100.0f)) good++;
    }
    __shared__ int s[256];
    s[tid] = good; __syncthreads();
    for (int st = 128; st > 0; st >>= 1) {
        if (tid < st) s[tid] += s[tid + st];
        __syncthreads();
    }
    if (tid == 0) { ctl[0] = 0u; ctl[1] = (s[0] >= 700) ? 0u : 1u; }
}

__global__ void k_sentinel(void* outv, const unsigned* ctl, float val) {
    int i = blockIdx.x * 256 + threadIdx.x;
    if (i >= 64000) return;
    if (ctl[1]) ((float*)outv)[i] = val;
    else ((bf16*)outv)[i] = __float2bfloat16(val);
}

// ---------------- mega prep ----------------
__device__ __forceinline__ void pack_convw_task(const void* w, uint2* wp, int Co, int f32,
                                                int bx, int tid) {
    int t = bx * 256 + tid;
    if (t >= Co * 41) return;
    int co = t / 41, k = t % 41;
    unsigned w0 = 0, w1 = 0;
    for (int c = 0; c < 32; c++)
        if (ldin(w, (co * 64 + c) * 41 + k, f32) > 0.f) w0 |= (1u << c);
    for (int c = 0; c < 32; c++)
        if (ldin(w, (co * 64 + 32 + c) * 41 + k, f32) > 0.f) w1 |= (1u << c);
    wp[t] = make_uint2(w0, w1);
}
__device__ __forceinline__ void pack_rows_task(const void* w, unsigned* wp, int rows, int F,
                                               int f32, int bx, int tid) {
    int Fw = F >> 5;
    int t = bx * 256 + tid;
    if (t >= rows * Fw) return;
    int r = t / Fw, wi = t % Fw;
    unsigned m = 0;
    for (int j = 0; j < 32; j++)
        if (ldin(w, (long)r * F + wi * 32 + j, f32) > 0.f) m |= (1u << j);
    wp[t] = m;
}

// conv1 A-fragment pack: K-layout kidx = 2*(c*44 + t) + h  (h: 0=hi,1=lo, same sign both)
// conv2 bit-packed weights (task 1): dword idx = (t*2 + p)*64 + lane; low16 = mask for
// m=2p, high16 = m=2p+1. Mask bit j = sign(w[co=16m+(lane&15)][ch=16*(lane>>4)+j][t]) > 0.
__global__ void k_prep(const void* x, const void* c1w, const void* c2w, const void* c3w,
                       const void* c4w, const void* c5w, const void* f1w, const void* f2w,
                       u16* afrag, unsigned* wb, uint2* w3p, uint2* w4p, uint2* w5p,
                       unsigned* fc1wp, unsigned* fc2wp, u64* stats, double* part0,
                       const unsigned* ctl) {
    int f32 = ctl[1];
    int task = blockIdx.y, bx = blockIdx.x, tid = threadIdx.x;
    switch (task) {
        case 0: {
            int t = bx * 256 + tid;
            if (t < 2304) {
                int m = t / 576, rem = t - m * 576;
                int ks = rem / 64, lane = rem - ks * 64;
                int li = lane & 15, hq = lane >> 4;
                int row = 16 * m + li;
                int g = 4 * ks + hq;
                int c = g / 11, t0 = 4 * (g - 11 * c);
                u16* outp = afrag + (size_t)t * 8;
                for (int i2 = 0; i2 < 4; i2++) {
                    int tt = t0 + i2;
                    u16 sv = 0;
                    if (g < 33 && tt <= 40) {
                        float wv = ldin(c1w, (row * 3 + c) * 41 + tt, f32);
                        sv = (wv > 0.f) ? (u16)0x3F80 : ((wv < 0.f) ? (u16)0xBF80 : (u16)0);
                    }
                    outp[2 * i2] = sv;       // hi slot
                    outp[2 * i2 + 1] = sv;   // lo slot (same sign)
                }
            }
        } break;
        case 1: {  // conv2 bit-packed weight masks
            int t = bx * 256 + tid;
            if (t < 5248) {
                int lane = t & 63, g = t >> 6;       // g = tt*2 + p, [0,82)
                int p = g & 1, tt = g >> 1;          // tt in [0,41)
                int li = lane & 15, hq = lane >> 4;
                unsigned d = 0;
#pragma unroll
                for (int mh = 0; mh < 2; mh++) {
                    int co = 16 * (2 * p + mh) + li;
                    unsigned msk = 0;
#pragma unroll
                    for (int j = 0; j < 16; j++) {
                        int c = 16 * hq + j;
                        if (ldin(c2w, (co * 64 + c) * 41 + tt, f32) > 0.f) msk |= 1u << j;
                    }
                    d |= msk << (16 * mh);
                }
                wb[t] = d;
            }
        } break;
        case 2: pack_convw_task(c3w, w3p, 64, f32, bx, tid); break;
        case 3: pack_convw_task(c4w, w4p, 64, f32, bx, tid); break;
        case 4: pack_convw_task(c5w, w5p, 32, f32, bx, tid); break;
        case 5: pack_rows_task(f1w, fc1wp, 1024, 832, f32, bx, tid); break;
        case 6: pack_rows_task(f2w, fc2wp, 1000, 1024, f32, bx, tid); break;
        case 7: {
            int i = bx * 256 + tid;
            if (i < 14400) stats[i] = 0ull;   // int-stats + yb(f64) + fixcnt
        } break;
        case 8: {
            if (bx >= 96) return;
            int c = bx >> 5, s = bx & 31;
            double s1 = 0, s2 = 0;
            for (int n = 0; n < 64; n++) {
                long base = (long)(n * 3 + c) * 16000;
                for (int l = s * 256 + tid; l < 16000; l += 32 * 256) {
                    double v = (double)ldin(x, base + l, f32);
                    s1 += v; s2 += v * v;
                }
            }
            __shared__ double a1[256], a2[256];
            a1[tid] = s1; a2[tid] = s2;
            __syncthreads();
            for (int st = 128; st > 0; st >>= 1) {
                if (tid < st) { a1[tid] += a1[tid + st]; a2[tid] += a2[tid + st]; }
                __syncthreads();
            }
            if (tid == 0) { part0[(c * 32 + s) * 2] = a1[0]; part0[(c * 32 + s) * 2 + 1] = a2[0]; }
        } break;
    }
}

// ---------------- conv1: bf16 MFMA with hi/lo split, SINGLE pass ----------------
__global__ __launch_bounds__(256, 3) void k_conv1(const void* __restrict__ x,
                                                  const double* __restrict__ part0,
                                                  const void* __restrict__ g0,
                                                  const void* __restrict__ b0,
                                                  const u16* __restrict__ afrag,
                                                  float* __restrict__ yq,
                                                  double* __restrict__ yb,
                                                  const unsigned* __restrict__ ctl) {
    __shared__ unsigned xs[8][140];        // parity streams, c=3 zero pad
    __shared__ float pool[4][48][20];      // [wave][pos][co] pad 16->20: 2-way banks
    __shared__ double sbuf[4][64][2];      // stats staging
    __shared__ float yst[16][68];          // per-m yq staging [c-within-m][lp-within-block]
    __shared__ float2 b0f[3];
    int f32 = ctl[1];
    int n = blockIdx.y, bx = blockIdx.x, tid = threadIdx.x;
    if (tid < 3) {   // fold bn0 finalize (f64 math, f32 apply)
        int c = tid;
        double s1 = 0, s2 = 0;
        for (int s = 0; s < 32; s++) { s1 += part0[(c * 32 + s) * 2]; s2 += part0[(c * 32 + s) * 2 + 1]; }
        double M = 64.0 * 16000.0;
        double mu = s1 / M, var = s2 / M - mu * mu;
        double A = (double)ldin(g0, c, f32) / sqrt(var + 1e-5);
        b0f[c] = make_float2((float)A, (float)((double)ldin(b0, c, f32) - mu * A));
    }
    __syncthreads();

    // fill parity streams (hi/lo bf16 interleaved per dword), f32 bn0 apply
    unsigned* xsf = &xs[0][0];
    for (int f = tid; f < 1120; f += 256) {
        int rc = f / 140, qi = f - rc * 140;
        int r = rc >> 2, c = rc & 3;
        unsigned dw = 0u;
        if (c < 3) {
            int xpos = 192 * bx + 2 * qi + r;
            if (xpos < 16000) {
                float2 pb = b0f[c];
                float v = fmaf(ldin(x, (long)(n * 3 + c) * 16000 + xpos, f32), pb.x, pb.y);
                v = fminf(fmaxf(v, -1.f), 1.f);
                bf16 h = __float2bfloat16(v);
                float hf = __bfloat162float(h);
                bf16 lo = __float2bfloat16(v - hf);
                dw = (unsigned)__bfloat16_as_ushort(h) | ((unsigned)__bfloat16_as_ushort(lo) << 16);
            }
        }
        xsf[f] = dw;
    }
    __syncthreads();

    int lane = tid & 63;
    int li = lane & 15, hq = lane >> 4;
    int w = __builtin_amdgcn_readfirstlane(tid >> 6);

    f32x4 zz = {0.f, 0.f, 0.f, 0.f};
    f32x4 acc[4][3];
#pragma unroll
    for (int m = 0; m < 4; m++)
#pragma unroll
        for (int nf = 0; nf < 3; nf++) acc[m][nf] = zz;

    int boff[3];
#pragma unroll
    for (int nf = 0; nf < 3; nf++) {
        int pl = 48 * w + 16 * nf + li;
        boff[nf] = (pl & 1) * 560 + (pl >> 1);
    }

    const bf16x8* ag = (const bf16x8*)afrag;
#pragma unroll 1
    for (int ks = 0; ks < 9; ks++) {
        int g = 4 * ks + hq;
        int c = g / 11;
        int kb = c * 140 + 4 * (g - 11 * c);
        bf16x8 a0 = ag[(0 * 9 + ks) * 64 + lane];
        bf16x8 a1 = ag[(1 * 9 + ks) * 64 + lane];
        bf16x8 a2 = ag[(2 * 9 + ks) * 64 + lane];
        bf16x8 a3 = ag[(3 * 9 + ks) * 64 + lane];
#pragma unroll
        for (int nf = 0; nf < 3; nf++) {
            const unsigned* bp = xsf + boff[nf] + kb;
            union { int4 i4; bf16x8 v; } u;
            u.i4 = make_int4(bp[0], bp[1], bp[2], bp[3]);
            acc[0][nf] = __builtin_amdgcn_mfma_f32_16x16x32_bf16(a0, u.v, acc[0][nf], 0, 0, 0);
            acc[1][nf] = __builtin_amdgcn_mfma_f32_16x16x32_bf16(a1, u.v, acc[1][nf], 0, 0, 0);
            acc[2][nf] = __builtin_amdgcn_mfma_f32_16x16x32_bf16(a2, u.v, acc[2][nf], 0, 0, 0);
            acc[3][nf] = __builtin_amdgcn_mfma_f32_16x16x32_bf16(a3, u.v, acc[3][nf], 0, 0, 0);
        }
    }

    int lp0 = 64 * bx + 16 * w;
#pragma unroll
    for (int m = 0; m < 4; m++) {        // FULL unroll: acc index must be static
#pragma unroll
        for (int nf = 0; nf < 3; nf++)
            *(f32x4*)&pool[w][16 * nf + li][4 * hq] = acc[m][nf];
        double s = 0.0, q = 0.0;
        float mqv[4];
#pragma unroll
        for (int i = 0; i < 4; i++) {
            int pc = hq + 4 * i;
            float mq = fmaxf(fmaxf(pool[w][3 * pc][li], pool[w][3 * pc + 1][li]),
                             pool[w][3 * pc + 2][li]);
            mqv[i] = mq;
            if (lp0 + pc < 5306) {
                double d = (double)mq;
                s += d; q += d * d;
            }
        }
        s += __shfl_down(s, 32, 64); s += __shfl_down(s, 16, 64);
        q += __shfl_down(q, 32, 64); q += __shfl_down(q, 16, 64);
        if (lane < 16) { sbuf[w][16 * m + lane][0] = s; sbuf[w][16 * m + lane][1] = q; }
        // stage mq for this m -> yst, then coalesced row write (values beyond
        // lp 5305 land in the YQS pad, never read by pack_y)
#pragma unroll
        for (int i = 0; i < 4; i++)
            yst[li][16 * w + hq + 4 * i] = mqv[i];
        __syncthreads();
        {
            int r = tid >> 4, c4 = (tid & 15) * 4;
            float4 v = *(const float4*)&yst[r][c4];
            *(float4*)&yq[((size_t)n * 64 + 16 * m + r) * YQS + 64 * bx + c4] = v;
        }
        __syncthreads();
    }
    if (tid < 64) {
        double s = sbuf[0][tid][0] + sbuf[1][tid][0] + sbuf[2][tid][0] + sbuf[3][tid][0];
        double q = sbuf[0][tid][1] + sbuf[1][tid][1] + sbuf[2][tid][1] + sbuf[3][tid][1];
        int sbk = bx & 15;
        atomicAdd(&yb[(tid * 16 + sbk) * 2], s);
        atomicAdd(&yb[(tid * 16 + sbk) * 2 + 1], q);
    }
}

// ---------------- pack_y: streaming sign + borderline list ----------------
__global__ void k_pack_y(const float* __restrict__ yq, const double* __restrict__ yb,
                         const void* g1, const void* b1,
                         uint2* __restrict__ xp,
                         unsigned* __restrict__ fixcnt, unsigned* __restrict__ fixlist,
                         const unsigned* __restrict__ ctl) {
    __shared__ double2 pqs[64];   // (A, B) per channel
    int f32 = ctl[1];
    int tid = threadIdx.x;
    if (tid < 64) {
        int c = tid;
        double s1 = 0, s2 = 0;
        for (int s = 0; s < 16; s++) { s1 += yb[(c * 16 + s) * 2]; s2 += yb[(c * 16 + s) * 2 + 1]; }
        double M = 64.0 * 5306.0;
        double mu = s1 / M;
        double var = s2 / M - mu * mu;
        double A = (double)ldin(g1, c, f32) / sqrt(var + 1e-5);
        pqs[c] = make_double2(A, (double)ldin(b1, c, f32) - mu * A);
    }
    __syncthreads();
    int n = blockIdx.y;
    int l = blockIdx.x * 256 + tid;
    if (l >= 5306) return;
    unsigned w0 = 0, w1 = 0;
    for (int c = 0; c < 64; c++) {
        double2 p = pqs[c];
        double v = (double)yq[((size_t)n * 64 + c) * YQS + l] * p.x + p.y;
        if (fabs(v) < 2e-3 * fabs(p.x)) {
            unsigned idx = atomicAdd(fixcnt, 1u);
            if (idx < FIXCAP) fixlist[idx] = ((unsigned)n << 19) | ((unsigned)c << 13) | (unsigned)l;
        }
        if (v > 0.0) { if (c < 32) w0 |= 1u << c; else w1 |= 1u << (c - 32); }
    }
    xp[(size_t)n * 5306 + l] = make_uint2(w0, w1);
}

// ---------------- k_fix: wave-per-entry f64 recompute of borderline outputs ----------------
// Round-12 PMC: 105us, VALUBusy 1.2%, Occupancy 1.1% — one THREAD per entry ran ~740
// serial dependent loads + re-derived entry-invariant bn0/bn1 params per entry. Now:
// params hoisted to LDS once per block; one WAVE per entry spreads the 123 (cc,k)
// terms over 64 lanes (<=2 each) + shfl f64 reduce. f64 sum order changes; reorder
// error ~1e-13 rel, far below the 2e-3 window margin.
__global__ __launch_bounds__(256) void k_fix(const unsigned* __restrict__ fixcnt,
                                             const unsigned* __restrict__ fixlist,
                                             const double* __restrict__ yb,
                                             const void* g1, const void* b1,
                                             const void* __restrict__ x,
                                             const void* __restrict__ c1w,
                                             const double* __restrict__ part0,
                                             const void* g0, const void* b0,
                                             unsigned* __restrict__ x2p,
                                             const unsigned* __restrict__ ctl) {
    __shared__ double2 pqs[64];   // bn1 (A,B) per channel
    __shared__ double2 p0s[3];    // bn0 (A0,B0) per input channel
    int f32 = ctl[1];
    int tid = threadIdx.x;
    if (tid < 64) {
        double s1 = 0, s2 = 0;
        for (int s = 0; s < 16; s++) { s1 += yb[(tid * 16 + s) * 2]; s2 += yb[(tid * 16 + s) * 2 + 1]; }
        double M = 64.0 * 5306.0;
        double mu = s1 / M, var = s2 / M - mu * mu;
        double A = (double)ldin(g1, tid, f32) / sqrt(var + 1e-5);
        pqs[tid] = make_double2(A, (double)ldin(b1, tid, f32) - mu * A);
    } else if (tid < 67) {
        int cc = tid - 64;
        double p1 = 0, p2 = 0;
        for (int s = 0; s < 32; s++) { p1 += part0[(cc * 32 + s) * 2]; p2 += part0[(cc * 32 + s) * 2 + 1]; }
        double M0 = 64.0 * 16000.0;
        double mu0 = p1 / M0, var0 = p2 / M0 - mu0 * mu0;
        double A0 = (double)ldin(g0, cc, f32) / sqrt(var0 + 1e-5);
        p0s[cc] = make_double2(A0, (double)ldin(b0, cc, f32) - mu0 * A0);
    }
    __syncthreads();
    unsigned cnt = min(*fixcnt, FIXCAP);
    int lane = tid & 63;
    int wid = blockIdx.x * 4 + (tid >> 6);
    int nw = gridDim.x * 4;
    for (unsigned t = wid; t < cnt; t += nw) {
        unsigned e = fixlist[t];
        int n = e >> 19, c = (e >> 13) & 63, l = e & 8191;
        double best = -1e300;
#pragma unroll 1
        for (int r = 0; r < 3; r++) {
            int pp = 3 * l + r;
            double acc = 0.0;
            for (int i = lane; i < 123; i += 64) {
                int cc = i / 41, k = i - cc * 41;
                float wf = ldin(c1w, (c * 3 + cc) * 41 + k, f32);
                double sgn = (wf > 0.f) ? 1.0 : ((wf < 0.f) ? -1.0 : 0.0);
                double2 P0 = p0s[cc];
                double xv = (double)ldin(x, (long)(n * 3 + cc) * 16000 + pp + 2 * k, f32);
                xv = fmin(fmax(xv * P0.x + P0.y, -1.0), 1.0);
                acc = fma(sgn, xv, acc);
            }
            for (int off = 32; off > 0; off >>= 1) acc += __shfl_down(acc, off, 64);
            acc = __shfl(acc, 0, 64);
            best = fmax(best, acc);
        }
        if (lane == 0) {
            double2 P = pqs[c];
            double v = best * P.x + P.y;
            unsigned* word = &x2p[((size_t)n * 5306 + l) * 2 + (c >> 5)];
            unsigned bit = 1u << (c & 31);
            if (v > 0.0) atomicOr(word, bit);
            else atomicAnd(word, ~bit);
        }
    }
}

// ---------------- conv2: i8 MFMA with {0,1} weights + column-sum correction ----------------
// grid (28, 64), single dispatch (round-12 split reverted: duplicated weight staging).
// Identity: x,w in {+-1}: d = 2*S1 - T; S1 = MFMA with A' = (w>0) in {0,1};
// T[pl] = 41-window sum of per-entry column sums cs = 2*popc(mask)-64. Exact ints.
__global__ __launch_bounds__(256, 3) void k_conv_i8(const uint2* __restrict__ xp,
                                                    const unsigned* __restrict__ wb,
                                                    u16* __restrict__ mout,
                                                    u64* __restrict__ stat, int nbase) {
    __shared__ __align__(16) char arena[44608];
    unsigned* xsd = (unsigned*)arena;                       // [0,21760): 2*136 x 80 B
    unsigned* wlds = (unsigned*)(arena + 21760);            // [21760,42752): 5248 dwords
    int* Tarr = (int*)(arena + 42752);                      // [42752,43520): 192 ints
    int* csA  = (int*)(arena + 43520);                      // [43520,44608): 272 ints
    int n = nbase + blockIdx.y, bx = blockIdx.x, tid = threadIdx.x;
    int base = 192 * bx;

    // stage bit-packed weights (once per block, coalesced)
    for (int i = tid; i < 5248; i += 256) wlds[i] = wb[i];

    // unpack input bit-masks -> +-1 i8 (byte = bit ? 0x01 : 0xFF) + column sums
    for (int e = tid; e < 272; e += 256) {
        int pos = base + e;
        int r = e & 1, qi = e >> 1;
        unsigned* dst = xsd + (r * 136 + qi) * 20;
        unsigned d[16];
        int cs = 0;
        if (pos < 5306) {
            uint2 mk = xp[(size_t)n * 5306 + pos];
            cs = 2 * (__popc(mk.x) + __popc(mk.y)) - 64;
#pragma unroll
            for (int dw = 0; dw < 8; dw++) {
                unsigned nib = (mk.x >> (4 * dw)) & 0xFu;
                unsigned sp = (nib * 0x00204081u) & 0x01010101u;
                d[dw] = ~(sp * 0xFEu);
            }
#pragma unroll
            for (int dw = 0; dw < 8; dw++) {
                unsigned nib = (mk.y >> (4 * dw)) & 0xFu;
                unsigned sp = (nib * 0x00204081u) & 0x01010101u;
                d[8 + dw] = ~(sp * 0xFEu);
            }
        } else {
#pragma unroll
            for (int dw = 0; dw < 16; dw++) d[dw] = 0u;
        }
#pragma unroll
        for (int v4 = 0; v4 < 4; v4++)
            *(uint4*)(dst + 4 * v4) = make_uint4(d[4 * v4], d[4 * v4 + 1],
                                                 d[4 * v4 + 2], d[4 * v4 + 3]);
        csA[r * 136 + qi] = cs;
    }
    __syncthreads();

    // T[pl] = 41-window sum of column sums for pl's parity stream (one-time)
    if (tid < 192) {
        int r = tid & 1, q = tid >> 1;
        int s = 0;
        for (int k = 0; k < 41; k++) s += csA[r * 136 + q + k];
        Tarr[tid] = s;
    }   // Tarr readers are after the post-K-loop barrier

    int lane = tid & 63;
    int li = lane & 15, hq = lane >> 4;
    int w = __builtin_amdgcn_readfirstlane(tid >> 6);

    i32x4 zz = {0, 0, 0, 0};
    i32x4 acc[4][3];
#pragma unroll
    for (int m = 0; m < 4; m++)
#pragma unroll
        for (int nf = 0; nf < 3; nf++) acc[m][nf] = zz;

    int boff[3];
#pragma unroll
    for (int nf = 0; nf < 3; nf++) {
        int pl = 48 * w + 16 * nf + li;
        boff[nf] = ((pl & 1) * 136 + (pl >> 1)) * 80 + 16 * hq;
    }

    const char* xsb = (const char*)xsd;
    const unsigned* wl = wlds + lane;

    // K-loop: pure LDS + VALU + MFMA; A' in {0,1} (cheap expansion)
#pragma unroll 1
    for (int t = 0; t < 41; t++) {
        unsigned w01 = wl[(t * 2 + 0) * 64];
        unsigned w23 = wl[(t * 2 + 1) * 64];
        i32x4 a0 = expand16_01(w01 & 0xFFFFu);
        i32x4 a1 = expand16_01(w01 >> 16);
        i32x4 a2 = expand16_01(w23 & 0xFFFFu);
        i32x4 a3 = expand16_01(w23 >> 16);
#pragma unroll
        for (int nf = 0; nf < 3; nf++) {
            i32x4 b = *(const i32x4*)(xsb + boff[nf] + t * 80);
            acc[0][nf] = __builtin_amdgcn_mfma_i32_16x16x64_i8(a0, b, acc[0][nf], 0, 0, 0);
            acc[1][nf] = __builtin_amdgcn_mfma_i32_16x16x64_i8(a1, b, acc[1][nf], 0, 0, 0);
            acc[2][nf] = __builtin_amdgcn_mfma_i32_16x16x64_i8(a2, b, acc[2][nf], 0, 0, 0);
            acc[3][nf] = __builtin_amdgcn_mfma_i32_16x16x64_i8(a3, b, acc[3][nf], 0, 0, 0);
        }
    }

    // epilogue (aliases arena[0,24576); Tarr/csA regions untouched):
    // d_r = 2*S1 - Tarr[pl]; pool-of-3 + stats; mt stage; coalesced write
    __syncthreads();   // all waves done reading xsd/wlds; Tarr writes visible
    int (*pooli)[48][20] = (int (*)[48][20])arena;          // 15360 B
    u16 (*mt)[72] = (u16 (*)[72])(arena + 15360);           // 9216 B
    int sbk = bx & 15;
#pragma unroll
    for (int m = 0; m < 4; m++) {        // FULL unroll: acc index must be static
#pragma unroll
        for (int nf = 0; nf < 3; nf++)
            *(i32x4*)&pooli[w][16 * nf + li][4 * hq] = acc[m][nf];
        int c = 16 * m + li;
        unsigned s = 0, q = 0;
#pragma unroll
        for (int i = 0; i < 4; i++) {
            int pc = hq + 4 * i;
            int d0 = 2 * pooli[w][3 * pc][li]     - Tarr[48 * w + 3 * pc];
            int d1 = 2 * pooli[w][3 * pc + 1][li] - Tarr[48 * w + 3 * pc + 1];
            int d2 = 2 * pooli[w][3 * pc + 2][li] - Tarr[48 * w + 3 * pc + 2];
            int d = max(max(d0, d1), d2);
            int mv = (2624 - d) >> 1;
            mt[c][16 * w + pc] = (u16)mv;
            int lp = 64 * bx + 16 * w + pc;
            if (lp < 1742) {
                s += (unsigned)mv;
                q += (unsigned)(mv * mv);
            }
        }
        s += __shfl_down(s, 32, 64); s += __shfl_down(s, 16, 64);
        q += __shfl_down(q, 32, 64); q += __shfl_down(q, 16, 64);
        if (lane < 16) {
            atomicAdd(&stat[((16 * m + lane) * 16 + sbk) * 2], (u64)s);
            atomicAdd(&stat[((16 * m + lane) * 16 + sbk) * 2 + 1], (u64)q);
        }
    }
    __syncthreads();
    {
        int c = tid >> 2, seg = tid & 3;
        int lp0 = 64 * bx + seg * 16;
        size_t rowb = ((size_t)n * 64 + c) * 1742;
        const u16* mp = &mt[c][seg * 16];
        if (lp0 + 15 < 1742) {
            unsigned* op = (unsigned*)(mout + rowb + lp0);
#pragma unroll
            for (int j = 0; j < 8; j++)
                op[j] = (unsigned)mp[2 * j] | ((unsigned)mp[2 * j + 1] << 16);
        } else {
            for (int j = 0; j < 16; j++) {
                int lp = lp0 + j;
                if (lp < 1742) mout[rowb + lp] = mp[j];
            }
        }
    }
}

// ---------------- binary conv with fused BN(m)+pack staging (conv3/4) ----------------
__global__ __launch_bounds__(256) void k_conv_binm(const u16* __restrict__ min_,
                                                   const u64* __restrict__ statIn,
                                                   const void* g, const void* b, double M,
                                                   const uint2* __restrict__ wp,
                                                   u16* __restrict__ mout,
                                                   u64* __restrict__ statOut,
                                                   int Lp, int Lin, int Co,
                                                   const unsigned* __restrict__ ctl) {
    __shared__ double2 pqs[64];
    __shared__ uint2 xt[272];
    int f32 = ctl[1];
    int n = blockIdx.y, tid = threadIdx.x;
    if (tid < 64) {
        int c = tid;
        u64 s1 = 0, s2 = 0;
        for (int s = 0; s < 16; s++) { s1 += statIn[(c * 16 + s) * 2]; s2 += statIn[(c * 16 + s) * 2 + 1]; }
        double mu = (double)s1 / M;
        double varm = (double)s2 / M - mu * mu;
        double A = (double)ldin(g, c, f32) / sqrt(4.0 * varm + 1e-5);
        pqs[c] = make_double2(-2.0 * A, 2.0 * A * mu + (double)ldin(b, c, f32));
    }
    __syncthreads();
    int base = blockIdx.x * 192;
    for (int i = tid; i < 272; i += 256) {
        int pos = base + i;
        unsigned w0 = 0, w1 = 0;
        if (pos < Lin) {
            const u16* mp = min_ + (size_t)n * 64 * Lin + pos;
#pragma unroll 4
            for (int c = 0; c < 32; c++) {
                double2 p = pqs[c];
                if ((double)mp[(size_t)c * Lin] * p.x + p.y > 0.0) w0 |= 1u << c;
            }
#pragma unroll 4
            for (int c = 0; c < 32; c++) {
                double2 p = pqs[c + 32];
                if ((double)mp[(size_t)(c + 32) * Lin] * p.x + p.y > 0.0) w1 |= 1u << c;
            }
        }
        xt[i] = make_uint2(w0, w1);
    }
    __syncthreads();

    int lane = tid & 63;
    int wave = __builtin_amdgcn_readfirstlane(tid >> 6);
    int co0 = blockIdx.z * 32 + wave * 8;
    int lp = blockIdx.x * 64 + lane;

    int acc[8][3] = {};
    uint2 xa = xt[3 * lane];
    for (int k = 0; k < 41; k++) {
        uint2 xb = xt[3 * lane + 2 * k + 1];
        uint2 xc = xt[3 * lane + 2 * k + 2];
#pragma unroll
        for (int j = 0; j < 8; j++) {
            uint2 w = wp[(co0 + j) * 41 + k];
            acc[j][0] += __popc(w.x ^ xa.x) + __popc(w.y ^ xa.y);
            acc[j][1] += __popc(w.x ^ xb.x) + __popc(w.y ^ xb.y);
            acc[j][2] += __popc(w.x ^ xc.x) + __popc(w.y ^ xc.y);
        }
        xa = xc;
    }
    bool ok = lp < Lp;
    int sb = blockIdx.x & 15;
#pragma unroll
    for (int j = 0; j < 8; j++) {
        int m = min(min(acc[j][0], acc[j][1]), acc[j][2]);
        if (ok) mout[((size_t)n * 64 + co0 + j) * Lp + lp] = (u16)m;
        if (statOut) {
            unsigned s = ok ? (unsigned)m : 0u;
            unsigned q = ok ? (unsigned)(m * m) : 0u;
            for (int off = 32; off > 0; off >>= 1) {
                s += __shfl_down(s, off, 64);
                q += __shfl_down(q, off, 64);
            }
            if (lane == 0) {
                atomicAdd(&statOut[((co0 + j) * 16 + sb) * 2], (u64)s);
                atomicAdd(&statOut[((co0 + j) * 16 + sb) * 2 + 1], (u64)q);
            }
        }
    }
}

// ---------------- conv5 + fc1 fused ----------------
__global__ void k_c5fc1(const u16* __restrict__ m4, const u64* __restrict__ s4,
                        const void* g4, const void* b4,
                        const uint2* __restrict__ w5p, const void* __restrict__ b5,
                        const unsigned* __restrict__ fc1wp, u16* __restrict__ acc1,
                        u64* __restrict__ s5, const unsigned* __restrict__ ctl) {
    __shared__ double2 pqs[64];
    __shared__ uint2 xt[280];
    __shared__ int m5s[32][26];
    __shared__ unsigned xw[26];
    int f32 = ctl[1];
    int n = blockIdx.x, tid = threadIdx.x;
    const int Lin = 158;
    if (tid < 64) {
        int c = tid;
        u64 s1 = 0, s2 = 0;
        for (int s = 0; s < 16; s++) { s1 += s4[(c * 16 + s) * 2]; s2 += s4[(c * 16 + s) * 2 + 1]; }
        double M = 64.0 * 158.0;
        double mu = (double)s1 / M;
        double varm = (double)s2 / M - mu * mu;
        double A = (double)ldin(g4, c, f32) / sqrt(4.0 * varm + 1e-5);
        pqs[c] = make_double2(-2.0 * A, 2.0 * A * mu + (double)ldin(b4, c, f32));
    }
    __syncthreads();
    for (int i = tid; i < 280; i += 256) {
        unsigned w0 = 0, w1 = 0;
        if (i < Lin) {
            const u16* mp = m4 + (size_t)n * 64 * Lin + i;
#pragma unroll 4
            for (int c = 0; c < 32; c++) {
                double2 p = pqs[c];
                if ((double)mp[(size_t)c * Lin] * p.x + p.y > 0.0) w0 |= 1u << c;
            }
#pragma unroll 4
            for (int c = 0; c < 32; c++) {
                double2 p = pqs[c + 32];
                if ((double)mp[(size_t)(c + 32) * Lin] * p.x + p.y > 0.0) w1 |= 1u << c;
            }
        }
        xt[i] = make_uint2(w0, w1);
    }
    __syncthreads();

    int lane = tid & 63;
    int wave = __builtin_amdgcn_readfirstlane(tid >> 6);
    int co0 = wave * 8;
    int acc[8][3] = {};
    uint2 xa = xt[3 * lane];
    for (int k = 0; k < 41; k++) {
        uint2 xb = xt[3 * lane + 2 * k + 1];
        uint2 xc = xt[3 * lane + 2 * k + 2];
#pragma unroll
        for (int j = 0; j < 8; j++) {
            uint2 w = w5p[(co0 + j) * 41 + k];
            acc[j][0] += __popc(w.x ^ xa.x) + __popc(w.y ^ xa.y);
            acc[j][1] += __popc(w.x ^ xb.x) + __popc(w.y ^ xb.y);
            acc[j][2] += __popc(w.x ^ xc.x) + __popc(w.y ^ xc.y);
        }
        xa = xc;
    }
    if (lane < 26) {
#pragma unroll
        for (int j = 0; j < 8; j++)
            m5s[co0 + j][lane] = min(min(acc[j][0], acc[j][1]), acc[j][2]);
    }
    __syncthreads();
    if (tid < 26) {
        unsigned mask = 0;
        for (int j = 0; j < 32; j++) {
            int f = tid * 32 + j, c = f / 26, l = f % 26;
            double yv = 2624.0 - 2.0 * (double)m5s[c][l] + (double)ldin(b5, c, f32);
            if (yv > 0.0) mask |= 1u << j;
        }
        xw[tid] = mask;
    }
    __syncthreads();
#pragma unroll
    for (int i = 0; i < 4; i++) {
        int j = tid + i * 256;
        unsigned a = 0;
        for (int w = 0; w < 26; w++) a += __popc(xw[w] ^ fc1wp[j * 26 + w]);
        acc1[n * 1024 + j] = (u16)a;
        atomicAdd(&s5[j * 2], (u64)a);
        atomicAdd(&s5[j * 2 + 1], (u64)(a * a));
    }
}

// ---------------- fc2 (+bn5 fold) and lsm (+bn6 fold) ----------------
__global__ void k_fc2(const u16* __restrict__ acc1, const u64* __restrict__ s5,
                      const void* g5, const void* b5, const unsigned* __restrict__ fc2wp,
                      u16* __restrict__ acc2, u64* __restrict__ s6, const unsigned* ctl) {
    __shared__ double2 pq5s[1024];
    __shared__ unsigned xw[32];
    int f32 = ctl[1];
    int n = blockIdx.y, tid = threadIdx.x;
    for (int f = tid; f < 1024; f += 256) {
        u64 a1 = s5[f * 2], a2 = s5[f * 2 + 1];
        double mu = (double)a1 / 64.0;
        double varm = (double)a2 / 64.0 - mu * mu;
        double A = (double)ldin(g5, f, f32) / sqrt(4.0 * varm + 1e-5);
        pq5s[f] = make_double2(-2.0 * A, 2.0 * A * mu + (double)ldin(b5, f, f32));
    }
    __syncthreads();
    if (tid < 32) {
        unsigned mask = 0;
        for (int j = 0; j < 32; j++) {
            int f = tid * 32 + j;
            double2 p = pq5s[f];
            if ((double)acc1[n * 1024 + f] * p.x + p.y > 0.0) mask |= 1u << j;
        }
        xw[tid] = mask;
    }
    __syncthreads();
    int j = blockIdx.x * 256 + tid;
    if (j >= 1000) return;
    unsigned a = 0;
    for (int w = 0; w < 32; w++) a += __popc(xw[w] ^ fc2wp[j * 32 + w]);
    acc2[n * 1000 + j] = (u16)a;
    atomicAdd(&s6[j * 2], (u64)a);
    atomicAdd(&s6[j * 2 + 1], (u64)(a * a));
}

__global__ void k_lsm(const u16* __restrict__ acc2, const u64* __restrict__ s6,
                      const void* g6, const void* b6, const unsigned* ctl, void* outv) {
    int n = blockIdx.x, tid = threadIdx.x;
    int f32 = ctl[1];
    __shared__ double red[256];
    double v[4];
    double mx = -1e300;
#pragma unroll
    for (int i = 0; i < 4; i++) {
        int j = tid + i * 256;
        if (j < 1000) {
            u64 a1 = s6[j * 2], a2 = s6[j * 2 + 1];
            double mu = (double)a1 / 64.0;
            double varm = (double)a2 / 64.0 - mu * mu;
            double A = (double)ldin(g6, j, f32) / sqrt(4.0 * varm + 1e-5);
            v[i] = (double)acc2[n * 1000 + j] * (-2.0 * A) + (2.0 * A * mu + (double)ldin(b6, j, f32));
            mx = fmax(mx, v[i]);
        } else v[i] = -1e300;
    }
    red[tid] = mx; __syncthreads();
    for (int s = 128; s > 0; s >>= 1) {
        if (tid < s) red[tid] = fmax(red[tid], red[tid + s]);
        __syncthreads();
    }
    mx = red[0]; __syncthreads();
    double sum = 0.0;
#pragma unroll
    for (int i = 0; i < 4; i++) {
        int j = tid + i * 256;
        if (j < 1000) sum += exp(v[i] - mx);
    }
    red[tid] = sum; __syncthreads();
    for (int s = 128; s > 0; s >>= 1) {
        if (tid < s) red[tid] += red[tid + s];
        __syncthreads();
    }
    double ls = log(red[0]);
#pragma unroll
    for (int i = 0; i < 4; i++) {
        int j = tid + i * 256;
        if (j < 1000) {
            float r = (float)(v[i] - mx - ls);
            if (!isfinite(r)) r = -700.0f;
            if (f32) ((float*)outv)[n * 1000 + j] = r;
            else ((bf16*)outv)[n * 1000 + j] = __float2bfloat16(r);
        }
    }
}

extern "C" void kernel_launch(void* const* d_in, const int* in_sizes, int n_in,
                              void* d_out, int out_size, void* d_ws, size_t ws_size,
                              hipStream_t stream) {
    const void* x       = d_in[0];
    const void* bn0_g   = d_in[1];
    const void* bn0_b   = d_in[2];
    const void* conv1_w = d_in[3];
    const void* bn1_g   = d_in[5];
    const void* bn1_b   = d_in[6];
    const void* conv2_w = d_in[7];
    const void* bn2_g   = d_in[9];
    const void* bn2_b   = d_in[10];
    const void* conv3_w = d_in[11];
    const void* bn3_g   = d_in[13];
    const void* bn3_b   = d_in[14];
    const void* conv4_w = d_in[15];
    const void* bn4_g   = d_in[17];
    const void* bn4_b   = d_in[18];
    const void* conv5_w = d_in[19];
    const void* conv5_b = d_in[20];
    const void* fc1_w   = d_in[21];
    const void* bn5_g   = d_in[23];
    const void* bn5_b   = d_in[24];
    const void* fc2_w   = d_in[25];
    const void* bn6_g   = d_in[27];
    const void* bn6_b   = d_in[28];

    char* wsb = (char*)d_ws;
    size_t off = 0;
    auto alloc = [&](size_t bytes) -> void* {
        off = (off + 255) & ~(size_t)255;
        void* p = wsb + off;
        off += bytes;
        return p;
    };

    unsigned* ctl   = (unsigned*)alloc(256);
    unsigned* x2p   = (unsigned*)alloc(2716672);       // 5306*64 uint2
    float*    yq    = (float*)alloc((size_t)64 * 64 * YQS * 4);  // 87 MB pooled conv1
    u16*      m2    = (u16*)alloc(14270464);
    u16*      m3    = (u16*)alloc(4538368);
    u16*      m4    = (u16*)alloc(1294336);
    u16*      acc1  = (u16*)alloc(131072);
    u16*      acc2  = (u16*)alloc(128000);
    u16*      afrag = (u16*)alloc(36864);              // conv1 bf16 A-fragments
    unsigned* wb    = (unsigned*)alloc(20992);         // conv2 bit-packed weights (lane layout)
    uint2*    w3p   = (uint2*)alloc(20992);
    uint2*    w4p   = (uint2*)alloc(20992);
    uint2*    w5p   = (uint2*)alloc(10496);
    unsigned* fc1wp = (unsigned*)alloc(106496);
    unsigned* fc2wp = (unsigned*)alloc(128000);
    u64*      stats = (u64*)alloc(14400 * 8);          // s2|s3|s4|s5|s6|..|yb(f64)|fixcnt
    double*   part0 = (double*)alloc(2048);
    unsigned* fixlist = (unsigned*)alloc(FIXCAP * 4);  // 4 MB
    size_t need = (off + 255) & ~(size_t)255;

    u64* s2 = stats;
    u64* s3 = stats + 2048;
    u64* s4 = stats + 4096;
    u64* s5 = stats + 6144;
    u64* s6 = stats + 8192;
    double* yb = (double*)(stats + 12288);             // 2048 f64 bn1 buckets
    unsigned* fixcnt = (unsigned*)(stats + 14340);

    k_probe<<<1, 256, 0, stream>>>(x, ctl);

    if (n_in != 29) {
        k_sentinel<<<250, 256, 0, stream>>>(d_out, ctl, -(3000.0f + (float)n_in));
        return;
    }
    if (ws_size < need) {
        k_sentinel<<<250, 256, 0, stream>>>(d_out, ctl, -1500.0f);
        return;
    }

    k_prep<<<dim3(125, 9), 256, 0, stream>>>(x, conv1_w, conv2_w, conv3_w, conv4_w, conv5_w,
                                             fc1_w, fc2_w, afrag, wb, w3p, w4p, w5p,
                                             fc1wp, fc2wp, stats, part0, ctl);

    // single conv pass: pooled mq -> yq (coalesced) + stats -> yb
    k_conv1<<<dim3(83, 64), 256, 0, stream>>>(x, part0, bn0_g, bn0_b, afrag, yq, yb, ctl);
    k_pack_y<<<dim3(21, 64), 256, 0, stream>>>(yq, yb, bn1_g, bn1_b, (uint2*)x2p,
                                               fixcnt, fixlist, ctl);
    k_fix<<<128, 256, 0, stream>>>(fixcnt, fixlist, yb, bn1_g, bn1_b, x, conv1_w,
                                   part0, bn0_g, bn0_b, x2p, ctl);

    k_conv_i8<<<dim3(28, 64), 256, 0, stream>>>((const uint2*)x2p, wb, m2, s2, 0);
    k_conv_binm<<<dim3(9, 64, 2), 256, 0, stream>>>(m2, s2, bn2_g, bn2_b, 64.0 * 1742.0,
                                                    w3p, m3, s3, 554, 1742, 64, ctl);
    k_conv_binm<<<dim3(3, 64, 2), 256, 0, stream>>>(m3, s3, bn3_g, bn3_b, 64.0 * 554.0,
                                                    w4p, m4, s4, 158, 554, 64, ctl);

    k_c5fc1<<<64, 256, 0, stream>>>(m4, s4, bn4_g, bn4_b, w5p, conv5_b, fc1wp, acc1, s5, ctl);
    k_fc2<<<dim3(4, 64), 256, 0, stream>>>(acc1, s5, bn5_g, bn5_b, fc2wp, acc2, s6, ctl);
    k_lsm<<<64, 256, 0, stream>>>(acc2, s6, bn6_g, bn6_b, ctl, d_out);
}